// Round 10
// baseline (521.902 us; speedup 1.0000x reference)
//
#include <hip/hip_runtime.h>
#include <hip/hip_bf16.h>

#define T_TOK 4096
#define DDIM  1024
#define HDIM  2048
#define NEXP  8

typedef __attribute__((ext_vector_type(4))) float f32x4;
typedef __attribute__((ext_vector_type(8))) short s16x8;
typedef __hip_bfloat16 bf16;

typedef const void __attribute__((address_space(1))) gvoid;
typedef void __attribute__((address_space(3))) svoid;

__device__ __forceinline__ void gload16(const void* g, void* l) {
    // async global->LDS, 16B/lane; LDS dest = wave-uniform base, HW adds lane*16
    __builtin_amdgcn_global_load_lds((gvoid*)g, (svoid*)l, 16, 0, 0);
}

// Swizzled LDS layout for a [128 rows][32 k] bf16 tile in 64 ldsrows x 64 elems
// (read map correctness-proven in R7): real row rr -> ldsrow rr>>1; chunk
// ch = 4*(rr&1) + kq/8 stored at slot ch ^ (ldsrow&7).
__device__ __forceinline__ int frag_off(int rr, int kq) {
    int lr = rr >> 1;
    int ch = ((rr & 1) << 2) + (kq >> 3);
    return lr * 64 + (ch ^ (lr & 7)) * 8;
}

// ---------------- router (fp64 acc, top-2 softmax) + fused x->bf16 cast ----------------
__global__ void router_cast_kernel(const float* __restrict__ x, const float* __restrict__ rw,
                                   int* __restrict__ r_e, float* __restrict__ r_w,
                                   bf16* __restrict__ xb) {
    int wave = threadIdx.x >> 6, lane = threadIdx.x & 63;
    int t = blockIdx.x * 4 + wave;
    const float* xr = x + (size_t)t * DDIM;
    bf16* xbr = xb + (size_t)t * DDIM;
    double acc[NEXP];
#pragma unroll
    for (int e = 0; e < NEXP; ++e) acc[e] = 0.0;
#pragma unroll
    for (int c = 0; c < 4; ++c) {
        int d = c * 256 + lane * 4;
        float4 v = *reinterpret_cast<const float4*>(xr + d);
        union { ushort4 u; bf16 h[4]; } o;
        o.h[0] = __float2bfloat16(v.x);
        o.h[1] = __float2bfloat16(v.y);
        o.h[2] = __float2bfloat16(v.z);
        o.h[3] = __float2bfloat16(v.w);
        *reinterpret_cast<ushort4*>(xbr + d) = o.u;
        const float* rw0 = rw + (size_t)d * NEXP;
#pragma unroll
        for (int j = 0; j < 4; ++j) {
            float xv = (&v.x)[j];
            const float* rwr = rw0 + j * NEXP;
#pragma unroll
            for (int e = 0; e < NEXP; ++e) acc[e] += (double)xv * (double)rwr[e];
        }
    }
#pragma unroll
    for (int e = 0; e < NEXP; ++e) {
#pragma unroll
        for (int off = 32; off > 0; off >>= 1) acc[e] += __shfl_down(acc[e], off);
    }
    if (lane == 0) {
        int i0 = 0; double v0 = acc[0];
#pragma unroll
        for (int e = 1; e < NEXP; ++e) if (acc[e] > v0) { v0 = acc[e]; i0 = e; }
        int i1 = -1; double v1 = -1e300;
#pragma unroll
        for (int e = 0; e < NEXP; ++e) { if (e == i0) continue; if (acc[e] > v1) { v1 = acc[e]; i1 = e; } }
        float w0 = 1.0f / (1.0f + expf((float)(v1 - v0)));
        float w1 = 1.0f - w0;
        r_e[2*t]   = i0; r_e[2*t+1] = i1;
        r_w[2*t]   = w0; r_w[2*t+1] = w1;
    }
}

// ---------------- fused binning: count + scan + fill in one block ----------------
__global__ void binning_kernel(const int* __restrict__ r_e, const float* __restrict__ r_w,
                               int* __restrict__ offs, int* __restrict__ list,
                               float* __restrict__ slot_w) {
    __shared__ int scnt[NEXP], scur[NEXP], soff[NEXP + 1];
    int tid = threadIdx.x;
    if (tid < NEXP) { scnt[tid] = 0; scur[tid] = 0; }
    __syncthreads();
    for (int i = tid; i < 2 * T_TOK; i += 512) atomicAdd(&scnt[r_e[i]], 1);
    __syncthreads();
    if (tid == 0) {
        int s = 0;
        for (int e = 0; e < NEXP; ++e) { soff[e] = s; s += scnt[e]; }
        soff[NEXP] = s;
    }
    __syncthreads();
    if (tid < NEXP + 1) offs[tid] = soff[tid];
    for (int i = tid; i < 2 * T_TOK; i += 512) {
        int e = r_e[i];
        int pos = atomicAdd(&scur[e], 1);
        int slot = soff[e] + pos;
        list[slot] = i >> 1;
        slot_w[slot] = r_w[i];
    }
}

// ---------------- transpose + fp32->bf16 cast (vectorized, generalized) ----------------
__global__ void transpose_cast_kernel(const float* __restrict__ in, bf16* __restrict__ out,
                                      int R, int C, int rmul, int roff, size_t outE) {
    __shared__ bf16 tile[64][68];
    const float* inp = in + (size_t)blockIdx.z * R * C;
    bf16* outp = out + (size_t)blockIdx.z * outE;
    int r0 = blockIdx.x * 64, c0 = blockIdx.y * 64;
    int tid = threadIdx.x;
#pragma unroll
    for (int i = 0; i < 4; ++i) {
        int idx = i * 256 + tid;
        int r = idx >> 4, c4 = (idx & 15) * 4;
        float4 v = *reinterpret_cast<const float4*>(inp + (size_t)(r0 + r) * C + c0 + c4);
        tile[r][c4 + 0] = __float2bfloat16(v.x);
        tile[r][c4 + 1] = __float2bfloat16(v.y);
        tile[r][c4 + 2] = __float2bfloat16(v.z);
        tile[r][c4 + 3] = __float2bfloat16(v.w);
    }
    __syncthreads();
#pragma unroll
    for (int i = 0; i < 4; ++i) {
        int idx = i * 256 + tid;
        int c = idx >> 4, r4 = (idx & 15) * 4;
        union { ushort4 u; bf16 h[4]; } w;
        w.h[0] = tile[r4 + 0][c];
        w.h[1] = tile[r4 + 1][c];
        w.h[2] = tile[r4 + 2][c];
        w.h[3] = tile[r4 + 3][c];
        *reinterpret_cast<ushort4*>(outp + ((size_t)(c0 + c) * rmul + roff) * R + r0 + r4) = w.u;
    }
}

// ======== pass 1: gate+up as ONE GEMM over interleaved wguT [2H][D] ========
// 128x128 tile, BK=32, 4 waves (2M x 2N, wave-out 64x64 -> 0.5 ds_read/MFMA).
// 32 KB double-buffered LDS -> 5 blocks/CU. Counted vmcnt(4), never drained
// mid-loop; swizzled LDS (0-conflict); setprio on MFMA cluster.
// Staging map (FIXED R10): wave-issue q writes elems q*512 + lane*8;
// lr = q*8 + (lane>>3), slot c = lane&7 holds global chunk c^(lr&7).
__global__ __launch_bounds__(256, 5)
void gateup_kernel(const bf16* __restrict__ xb, const bf16* __restrict__ wguT,
                   const int* __restrict__ offs, const int* __restrict__ list,
                   bf16* __restrict__ hbuf) {
    int e = blockIdx.z;
    int base = offs[e];
    int ne = offs[e + 1] - base;
    int m0 = blockIdx.y * 128;
    if (m0 >= ne) return;
    int n0 = blockIdx.x * 128;   // in 2H=4096 interleaved space

    __shared__ bf16 As[2][4096];   // 128 rows x 32 k (8 KB/buf), swizzled
    __shared__ bf16 Bs[2][4096];

    int tid = threadIdx.x, lane = tid & 63, wid = tid >> 6;

    const bf16* bbase = wguT + (size_t)e * (2 * HDIM) * DDIM + (size_t)n0 * DDIM;

    const bf16* aS[2]; const bf16* bS[2];
    int sdst[2];
#pragma unroll
    for (int j = 0; j < 2; ++j) {
        int q = wid + j * 4;                    // wave-issue index 0..7
        int lr = q * 8 + (lane >> 3);           // ldsrow this lane writes
        int ch = (lane & 7) ^ (lr & 7);         // global chunk stored at this slot
        int rr = 2 * lr + (ch >> 2);            // real tile row
        int koff = (ch & 3) * 8;                // k elem offset
        int r = m0 + rr; if (r > ne - 1) r = ne - 1;   // clamp: read-only, never stored
        aS[j] = xb + (size_t)list[base + r] * DDIM + koff;
        bS[j] = bbase + (size_t)rr * DDIM + koff;
        sdst[j] = q * 512;                      // wave-uniform elem offset (512 elems/issue)
    }

    int rl = lane & 15, kq = 8 * (lane >> 4);
    int wrow = (wid >> 1) * 64;      // 2 M waves
    int wcol = (wid & 1) * 64;       // 2 N waves
    int offA[4], offB[4];
#pragma unroll
    for (int mi = 0; mi < 4; ++mi) offA[mi] = frag_off(wrow + mi * 16 + rl, kq);
#pragma unroll
    for (int ni = 0; ni < 4; ++ni) offB[ni] = frag_off(wcol + ni * 16 + rl, kq);

    f32x4 zero4 = {0.f, 0.f, 0.f, 0.f};
    f32x4 acc[4][4];
#pragma unroll
    for (int mi = 0; mi < 4; ++mi)
#pragma unroll
        for (int ni = 0; ni < 4; ++ni) acc[mi][ni] = zero4;

    const int nk = DDIM / 32;   // 32

#define GU_STAGE(tt, buf)                                     \
    {                                                         \
        int k0 = (tt) * 32;                                   \
        gload16(aS[0] + k0, &As[buf][sdst[0]]);               \
        gload16(aS[1] + k0, &As[buf][sdst[1]]);               \
        gload16(bS[0] + k0, &Bs[buf][sdst[0]]);               \
        gload16(bS[1] + k0, &Bs[buf][sdst[1]]);               \
    }

    // prologue: stage tiles 0,1 (4 loads each); wait tile0, keep tile1 in flight
    GU_STAGE(0, 0);
    GU_STAGE(1, 1);
    asm volatile("s_waitcnt vmcnt(4)" ::: "memory");
    __builtin_amdgcn_s_barrier();

    for (int t = 0; t < nk; ++t) {
        const bf16* Ab = As[t & 1];
        const bf16* Bb = Bs[t & 1];
        s16x8 a[4], b[4];
#pragma unroll
        for (int mi = 0; mi < 4; ++mi) a[mi] = *reinterpret_cast<const s16x8*>(Ab + offA[mi]);
#pragma unroll
        for (int ni = 0; ni < 4; ++ni) b[ni] = *reinterpret_cast<const s16x8*>(Bb + offB[ni]);
        __builtin_amdgcn_s_setprio(1);
#pragma unroll
        for (int mi = 0; mi < 4; ++mi)
#pragma unroll
            for (int ni = 0; ni < 4; ++ni)
                acc[mi][ni] = __builtin_amdgcn_mfma_f32_16x16x32_bf16(a[mi], b[ni], acc[mi][ni], 0, 0, 0);
        __builtin_amdgcn_s_setprio(0);
        __builtin_amdgcn_sched_barrier(0);
        __builtin_amdgcn_s_barrier();                 // buf[t&1] free
        if (t + 2 < nk) GU_STAGE(t + 2, t & 1);       // in flight: t+1(4) + t+2(4)
        if (t + 1 < nk) {
            if (t + 2 < nk) asm volatile("s_waitcnt vmcnt(4)" ::: "memory");
            else            asm volatile("s_waitcnt vmcnt(0)" ::: "memory");
            __builtin_amdgcn_s_barrier();             // tile t+1 fully in LDS
        }
    }
#undef GU_STAGE

    // epilogue: even col = gate, odd col = up; pair via shfl_xor(1), even lanes store.
    int rbase = (lane >> 4) * 4, cbase = lane & 15;
    bool evenlane = (lane & 1) == 0;
#pragma unroll
    for (int mi = 0; mi < 4; ++mi) {
#pragma unroll
        for (int ni = 0; ni < 4; ++ni) {
#pragma unroll
            for (int r = 0; r < 4; ++r) {
                float own = acc[mi][ni][r];
                float oth = __shfl_xor(own, 1);
                int row = m0 + wrow + mi * 16 + rbase + r;
                if (evenlane && row < ne) {
                    float g = own, u = oth;
                    float h = (g / (1.0f + expf(-g))) * u;
                    int hcol = (n0 + wcol + ni * 16 + cbase) >> 1;
                    hbuf[(size_t)(base + row) * HDIM + hcol] = __float2bfloat16(h);
                }
            }
        }
    }
}

// ======== pass 2: down GEMM 128x128, BK=32, same geometry, fused atomic combine ========
// y zeroed first; each element gets exactly 2 commutative fp32 adds -> deterministic.
__global__ __launch_bounds__(256, 5)
void down_kernel(const bf16* __restrict__ hbuf, const bf16* __restrict__ wdT,
                 const int* __restrict__ offs, const int* __restrict__ list,
                 const float* __restrict__ slot_w, float* __restrict__ y) {
    int e = blockIdx.z;
    int base = offs[e];
    int ne = offs[e + 1] - base;
    int m0 = blockIdx.y * 128;
    if (m0 >= ne) return;
    int n0 = blockIdx.x * 128;   // d-tile

    __shared__ bf16 As[2][4096];
    __shared__ bf16 Bs[2][4096];

    int tid = threadIdx.x, lane = tid & 63, wid = tid >> 6;

    const bf16* bbase = wdT + (size_t)e * DDIM * HDIM + (size_t)n0 * HDIM;

    const bf16* aS[2]; const bf16* bS[2];
    int sdst[2];
#pragma unroll
    for (int j = 0; j < 2; ++j) {
        int q = wid + j * 4;
        int lr = q * 8 + (lane >> 3);
        int ch = (lane & 7) ^ (lr & 7);
        int rr = 2 * lr + (ch >> 2);
        int koff = (ch & 3) * 8;
        int r = m0 + rr; if (r > ne - 1) r = ne - 1;
        aS[j] = hbuf + (size_t)(base + r) * HDIM + koff;
        bS[j] = bbase + (size_t)rr * HDIM + koff;
        sdst[j] = q * 512;
    }

    int rl = lane & 15, kq = 8 * (lane >> 4);
    int wrow = (wid >> 1) * 64;
    int wcol = (wid & 1) * 64;
    int offA[4], offB[4];
#pragma unroll
    for (int mi = 0; mi < 4; ++mi) offA[mi] = frag_off(wrow + mi * 16 + rl, kq);
#pragma unroll
    for (int ni = 0; ni < 4; ++ni) offB[ni] = frag_off(wcol + ni * 16 + rl, kq);

    f32x4 zero4 = {0.f, 0.f, 0.f, 0.f};
    f32x4 acc[4][4];
#pragma unroll
    for (int mi = 0; mi < 4; ++mi)
#pragma unroll
        for (int ni = 0; ni < 4; ++ni) acc[mi][ni] = zero4;

    const int nk = HDIM / 32;   // 64

#define DN_STAGE(tt, buf)                                     \
    {                                                         \
        int k0 = (tt) * 32;                                   \
        gload16(aS[0] + k0, &As[buf][sdst[0]]);               \
        gload16(aS[1] + k0, &As[buf][sdst[1]]);               \
        gload16(bS[0] + k0, &Bs[buf][sdst[0]]);               \
        gload16(bS[1] + k0, &Bs[buf][sdst[1]]);               \
    }

    DN_STAGE(0, 0);
    DN_STAGE(1, 1);
    asm volatile("s_waitcnt vmcnt(4)" ::: "memory");
    __builtin_amdgcn_s_barrier();

    for (int t = 0; t < nk; ++t) {
        const bf16* Ab = As[t & 1];
        const bf16* Bb = Bs[t & 1];
        s16x8 a[4], b[4];
#pragma unroll
        for (int mi = 0; mi < 4; ++mi) a[mi] = *reinterpret_cast<const s16x8*>(Ab + offA[mi]);
#pragma unroll
        for (int ni = 0; ni < 4; ++ni) b[ni] = *reinterpret_cast<const s16x8*>(Bb + offB[ni]);
        __builtin_amdgcn_s_setprio(1);
#pragma unroll
        for (int mi = 0; mi < 4; ++mi)
#pragma unroll
            for (int ni = 0; ni < 4; ++ni)
                acc[mi][ni] = __builtin_amdgcn_mfma_f32_16x16x32_bf16(a[mi], b[ni], acc[mi][ni], 0, 0, 0);
        __builtin_amdgcn_s_setprio(0);
        __builtin_amdgcn_sched_barrier(0);
        __builtin_amdgcn_s_barrier();
        if (t + 2 < nk) DN_STAGE(t + 2, t & 1);
        if (t + 1 < nk) {
            if (t + 2 < nk) asm volatile("s_waitcnt vmcnt(4)" ::: "memory");
            else            asm volatile("s_waitcnt vmcnt(0)" ::: "memory");
            __builtin_amdgcn_s_barrier();
        }
    }
#undef DN_STAGE

    // epilogue: y[tok][col] += w * acc  (2 adds per element, commutative -> deterministic)
    int rbase = (lane >> 4) * 4, cbase = lane & 15;
#pragma unroll
    for (int mi = 0; mi < 4; ++mi) {
#pragma unroll
        for (int r = 0; r < 4; ++r) {
            int row = m0 + wrow + mi * 16 + rbase + r;
            if (row < ne) {
                int slot = base + row;
                int tok = list[slot];
                float w = slot_w[slot];
                float* yrow = y + (size_t)tok * DDIM + n0 + wcol + cbase;
#pragma unroll
                for (int ni = 0; ni < 4; ++ni)
                    atomicAdd(yrow + ni * 16, w * acc[mi][ni][r]);
            }
        }
    }
}

extern "C" void kernel_launch(void* const* d_in, const int* in_sizes, int n_in,
                              void* d_out, int out_size, void* d_ws, size_t ws_size,
                              hipStream_t stream) {
    const float* x  = (const float*)d_in[0];
    const float* rw = (const float*)d_in[1];
    const float* wg = (const float*)d_in[2];
    const float* wu = (const float*)d_in[3];
    const float* wd = (const float*)d_in[4];
    float* y = (float*)d_out;

    char* ws = (char*)d_ws;
    int*   r_e    = (int*)  (ws + 0);           // 2T ints
    float* r_w    = (float*)(ws + 32768);       // 2T floats
    int*   offs   = (int*)  (ws + 65600);       // 9
    int*   list   = (int*)  (ws + 65664);       // 2T ints
    float* slot_w = (float*)(ws + 98432);       // 2T floats
    bf16*  xb     = (bf16*) (ws + 1048576ull);      // 8 MB
    bf16*  wguT   = (bf16*) (ws + 16777216ull);     // 64 MB  [E][2H][D] interleaved g/u
    bf16*  wdT    = (bf16*) (ws + 83886080ull);     // 32 MB  [E][D][H]
    bf16*  hbuf   = (bf16*) (ws + 117440512ull);    // 32 MB  [slot][H]

    // weight transposes + casts (wg/wu interleaved into wguT rows 2h / 2h+1)
    transpose_cast_kernel<<<dim3(DDIM / 64, HDIM / 64, NEXP), 256, 0, stream>>>(
        wg, wguT, DDIM, HDIM, 2, 0, (size_t)2 * HDIM * DDIM);
    transpose_cast_kernel<<<dim3(DDIM / 64, HDIM / 64, NEXP), 256, 0, stream>>>(
        wu, wguT, DDIM, HDIM, 2, 1, (size_t)2 * HDIM * DDIM);
    transpose_cast_kernel<<<dim3(HDIM / 64, DDIM / 64, NEXP), 256, 0, stream>>>(
        wd, wdT, HDIM, DDIM, 1, 0, (size_t)DDIM * HDIM);

    // routing (+ fused x cast) and binning
    router_cast_kernel<<<dim3(T_TOK / 4), 256, 0, stream>>>(x, rw, r_e, r_w, xb);
    binning_kernel<<<dim3(1), 512, 0, stream>>>(r_e, r_w, offs, list, slot_w);

    // zero y (down accumulates into it atomically)
    hipMemsetAsync(d_out, 0, (size_t)out_size * sizeof(float), stream);

    // expert GEMMs (grouped, worst-case grid with early-exit)
    gateup_kernel<<<dim3(2 * HDIM / 128, T_TOK / 128, NEXP), 256, 0, stream>>>(xb, wguT, offs, list, hbuf);
    down_kernel<<<dim3(DDIM / 128, T_TOK / 128, NEXP), 256, 0, stream>>>(hbuf, wdT, offs, list, slot_w, y);
}

// Round 11
// 294.917 us; speedup vs baseline: 1.7697x; 1.7697x over previous
//
#include <hip/hip_runtime.h>
#include <hip/hip_bf16.h>

#define T_TOK 4096
#define DDIM  1024
#define HDIM  2048
#define NEXP  8

typedef __attribute__((ext_vector_type(4))) float f32x4;
typedef __attribute__((ext_vector_type(8))) short s16x8;
typedef __hip_bfloat16 bf16;

typedef const void __attribute__((address_space(1))) gvoid;
typedef void __attribute__((address_space(3))) svoid;

__device__ __forceinline__ void gload16(const void* g, void* l) {
    // async global->LDS, 16B/lane; LDS dest = wave-uniform base, HW adds lane*16
    __builtin_amdgcn_global_load_lds((gvoid*)g, (svoid*)l, 16, 0, 0);
}

// Swizzled LDS layout for a [128 rows][32 k] bf16 tile in 64 ldsrows x 64 elems
// (read map + staging map correctness-proven in R10): real row rr -> ldsrow rr>>1;
// chunk ch = 4*(rr&1) + kq/8 stored at slot ch ^ (ldsrow&7).
__device__ __forceinline__ int frag_off(int rr, int kq) {
    int lr = rr >> 1;
    int ch = ((rr & 1) << 2) + (kq >> 3);
    return lr * 64 + (ch ^ (lr & 7)) * 8;
}

// ---------------- router (fp64 acc, top-2 softmax) + fused x->bf16 cast ----------------
__global__ void router_cast_kernel(const float* __restrict__ x, const float* __restrict__ rw,
                                   int* __restrict__ r_e, float* __restrict__ r_w,
                                   bf16* __restrict__ xb) {
    int wave = threadIdx.x >> 6, lane = threadIdx.x & 63;
    int t = blockIdx.x * 4 + wave;
    const float* xr = x + (size_t)t * DDIM;
    bf16* xbr = xb + (size_t)t * DDIM;
    double acc[NEXP];
#pragma unroll
    for (int e = 0; e < NEXP; ++e) acc[e] = 0.0;
#pragma unroll
    for (int c = 0; c < 4; ++c) {
        int d = c * 256 + lane * 4;
        float4 v = *reinterpret_cast<const float4*>(xr + d);
        union { ushort4 u; bf16 h[4]; } o;
        o.h[0] = __float2bfloat16(v.x);
        o.h[1] = __float2bfloat16(v.y);
        o.h[2] = __float2bfloat16(v.z);
        o.h[3] = __float2bfloat16(v.w);
        *reinterpret_cast<ushort4*>(xbr + d) = o.u;
        const float* rw0 = rw + (size_t)d * NEXP;
#pragma unroll
        for (int j = 0; j < 4; ++j) {
            float xv = (&v.x)[j];
            const float* rwr = rw0 + j * NEXP;
#pragma unroll
            for (int e = 0; e < NEXP; ++e) acc[e] += (double)xv * (double)rwr[e];
        }
    }
#pragma unroll
    for (int e = 0; e < NEXP; ++e) {
#pragma unroll
        for (int off = 32; off > 0; off >>= 1) acc[e] += __shfl_down(acc[e], off);
    }
    if (lane == 0) {
        int i0 = 0; double v0 = acc[0];
#pragma unroll
        for (int e = 1; e < NEXP; ++e) if (acc[e] > v0) { v0 = acc[e]; i0 = e; }
        int i1 = -1; double v1 = -1e300;
#pragma unroll
        for (int e = 0; e < NEXP; ++e) { if (e == i0) continue; if (acc[e] > v1) { v1 = acc[e]; i1 = e; } }
        float w0 = 1.0f / (1.0f + expf((float)(v1 - v0)));
        float w1 = 1.0f - w0;
        r_e[2*t]   = i0; r_e[2*t+1] = i1;
        r_w[2*t]   = w0; r_w[2*t+1] = w1;
    }
}

// ---------------- fused binning: count + scan + fill in one block ----------------
__global__ void binning_kernel(const int* __restrict__ r_e, const float* __restrict__ r_w,
                               int* __restrict__ offs, int* __restrict__ list,
                               float* __restrict__ slot_w) {
    __shared__ int scnt[NEXP], scur[NEXP], soff[NEXP + 1];
    int tid = threadIdx.x;
    if (tid < NEXP) { scnt[tid] = 0; scur[tid] = 0; }
    __syncthreads();
    for (int i = tid; i < 2 * T_TOK; i += 512) atomicAdd(&scnt[r_e[i]], 1);
    __syncthreads();
    if (tid == 0) {
        int s = 0;
        for (int e = 0; e < NEXP; ++e) { soff[e] = s; s += scnt[e]; }
        soff[NEXP] = s;
    }
    __syncthreads();
    if (tid < NEXP + 1) offs[tid] = soff[tid];
    for (int i = tid; i < 2 * T_TOK; i += 512) {
        int e = r_e[i];
        int pos = atomicAdd(&scur[e], 1);
        int slot = soff[e] + pos;
        list[slot] = i >> 1;
        slot_w[slot] = r_w[i];
    }
}

// ---------------- transpose + fp32->bf16 cast (vectorized, generalized) ----------------
__global__ void transpose_cast_kernel(const float* __restrict__ in, bf16* __restrict__ out,
                                      int R, int C, int rmul, int roff, size_t outE) {
    __shared__ bf16 tile[64][68];
    const float* inp = in + (size_t)blockIdx.z * R * C;
    bf16* outp = out + (size_t)blockIdx.z * outE;
    int r0 = blockIdx.x * 64, c0 = blockIdx.y * 64;
    int tid = threadIdx.x;
#pragma unroll
    for (int i = 0; i < 4; ++i) {
        int idx = i * 256 + tid;
        int r = idx >> 4, c4 = (idx & 15) * 4;
        float4 v = *reinterpret_cast<const float4*>(inp + (size_t)(r0 + r) * C + c0 + c4);
        tile[r][c4 + 0] = __float2bfloat16(v.x);
        tile[r][c4 + 1] = __float2bfloat16(v.y);
        tile[r][c4 + 2] = __float2bfloat16(v.z);
        tile[r][c4 + 3] = __float2bfloat16(v.w);
    }
    __syncthreads();
#pragma unroll
    for (int i = 0; i < 4; ++i) {
        int idx = i * 256 + tid;
        int c = idx >> 4, r4 = (idx & 15) * 4;
        union { ushort4 u; bf16 h[4]; } w;
        w.h[0] = tile[r4 + 0][c];
        w.h[1] = tile[r4 + 1][c];
        w.h[2] = tile[r4 + 2][c];
        w.h[3] = tile[r4 + 3][c];
        *reinterpret_cast<ushort4*>(outp + ((size_t)(c0 + c) * rmul + roff) * R + r0 + r4) = w.u;
    }
}

// ======== pass 1: gate+up as ONE GEMM over interleaved wguT [2H][D] ========
// 128x128 tile, BK=32, 4 waves (2M x 2N, wave-out 64x64 -> 0.5 ds_read/MFMA).
// 32 KB double-buffered LDS -> HW can fit 5 blocks/CU (VGPR ~88 <= 102).
// Counted vmcnt(4), never drained mid-loop; 0-conflict swizzle; setprio.
// __launch_bounds__(256,2): VGPR cap 256 -> NO allocator squeeze (R10 lesson:
// (256,5) forced 48 VGPR + 240MB spill; the hint must not cap below need).
__global__ __launch_bounds__(256, 2)
void gateup_kernel(const bf16* __restrict__ xb, const bf16* __restrict__ wguT,
                   const int* __restrict__ offs, const int* __restrict__ list,
                   bf16* __restrict__ hbuf) {
    int e = blockIdx.z;
    int base = offs[e];
    int ne = offs[e + 1] - base;
    int m0 = blockIdx.y * 128;
    if (m0 >= ne) return;
    int n0 = blockIdx.x * 128;   // in 2H=4096 interleaved space

    __shared__ bf16 As[2][4096];   // 128 rows x 32 k (8 KB/buf), swizzled
    __shared__ bf16 Bs[2][4096];

    int tid = threadIdx.x, lane = tid & 63, wid = tid >> 6;

    const bf16* bbase = wguT + (size_t)e * (2 * HDIM) * DDIM + (size_t)n0 * DDIM;

    // staging map (proven R10): wave-issue q writes elems q*512 + lane*8;
    // lr = q*8 + (lane>>3), slot c = lane&7 holds global chunk c^(lr&7).
    const bf16* aS[2]; const bf16* bS[2];
    int sdst[2];
#pragma unroll
    for (int j = 0; j < 2; ++j) {
        int q = wid + j * 4;
        int lr = q * 8 + (lane >> 3);
        int ch = (lane & 7) ^ (lr & 7);
        int rr = 2 * lr + (ch >> 2);
        int koff = (ch & 3) * 8;
        int r = m0 + rr; if (r > ne - 1) r = ne - 1;   // clamp: read-only, never stored
        aS[j] = xb + (size_t)list[base + r] * DDIM + koff;
        bS[j] = bbase + (size_t)rr * DDIM + koff;
        sdst[j] = q * 512;
    }

    int rl = lane & 15, kq = 8 * (lane >> 4);
    int wrow = (wid >> 1) * 64;      // 2 M waves
    int wcol = (wid & 1) * 64;       // 2 N waves
    int offA[4], offB[4];
#pragma unroll
    for (int mi = 0; mi < 4; ++mi) offA[mi] = frag_off(wrow + mi * 16 + rl, kq);
#pragma unroll
    for (int ni = 0; ni < 4; ++ni) offB[ni] = frag_off(wcol + ni * 16 + rl, kq);

    f32x4 zero4 = {0.f, 0.f, 0.f, 0.f};
    f32x4 acc[4][4];
#pragma unroll
    for (int mi = 0; mi < 4; ++mi)
#pragma unroll
        for (int ni = 0; ni < 4; ++ni) acc[mi][ni] = zero4;

    const int nk = DDIM / 32;   // 32

#define GU_STAGE(tt, buf)                                     \
    {                                                         \
        int k0 = (tt) * 32;                                   \
        gload16(aS[0] + k0, &As[buf][sdst[0]]);               \
        gload16(aS[1] + k0, &As[buf][sdst[1]]);               \
        gload16(bS[0] + k0, &Bs[buf][sdst[0]]);               \
        gload16(bS[1] + k0, &Bs[buf][sdst[1]]);               \
    }

    // prologue: stage tiles 0,1 (4 loads each); wait tile0, keep tile1 in flight
    GU_STAGE(0, 0);
    GU_STAGE(1, 1);
    asm volatile("s_waitcnt vmcnt(4)" ::: "memory");
    __builtin_amdgcn_s_barrier();

    for (int t = 0; t < nk; ++t) {
        const bf16* Ab = As[t & 1];
        const bf16* Bb = Bs[t & 1];
        s16x8 a[4], b[4];
#pragma unroll
        for (int mi = 0; mi < 4; ++mi) a[mi] = *reinterpret_cast<const s16x8*>(Ab + offA[mi]);
#pragma unroll
        for (int ni = 0; ni < 4; ++ni) b[ni] = *reinterpret_cast<const s16x8*>(Bb + offB[ni]);
        __builtin_amdgcn_s_setprio(1);
#pragma unroll
        for (int mi = 0; mi < 4; ++mi)
#pragma unroll
            for (int ni = 0; ni < 4; ++ni)
                acc[mi][ni] = __builtin_amdgcn_mfma_f32_16x16x32_bf16(a[mi], b[ni], acc[mi][ni], 0, 0, 0);
        __builtin_amdgcn_s_setprio(0);
        __builtin_amdgcn_sched_barrier(0);
        __builtin_amdgcn_s_barrier();                 // buf[t&1] free
        if (t + 2 < nk) GU_STAGE(t + 2, t & 1);       // in flight: t+1(4) + t+2(4)
        if (t + 1 < nk) {
            if (t + 2 < nk) asm volatile("s_waitcnt vmcnt(4)" ::: "memory");
            else            asm volatile("s_waitcnt vmcnt(0)" ::: "memory");
            __builtin_amdgcn_s_barrier();             // tile t+1 fully in LDS
        }
    }
#undef GU_STAGE

    // epilogue: even col = gate, odd col = up; pair via shfl_xor(1), even lanes store.
    int rbase = (lane >> 4) * 4, cbase = lane & 15;
    bool evenlane = (lane & 1) == 0;
#pragma unroll
    for (int mi = 0; mi < 4; ++mi) {
#pragma unroll
        for (int ni = 0; ni < 4; ++ni) {
#pragma unroll
            for (int r = 0; r < 4; ++r) {
                float own = acc[mi][ni][r];
                float oth = __shfl_xor(own, 1);
                int row = m0 + wrow + mi * 16 + rbase + r;
                if (evenlane && row < ne) {
                    float g = own, u = oth;
                    float h = (g / (1.0f + expf(-g))) * u;
                    int hcol = (n0 + wcol + ni * 16 + cbase) >> 1;
                    hbuf[(size_t)(base + row) * HDIM + hcol] = __float2bfloat16(h);
                }
            }
        }
    }
}

// ======== pass 2: down GEMM 128x128, BK=32, same geometry, fused atomic combine ========
// y zeroed first; each element gets exactly 2 commutative fp32 adds -> deterministic.
__global__ __launch_bounds__(256, 2)
void down_kernel(const bf16* __restrict__ hbuf, const bf16* __restrict__ wdT,
                 const int* __restrict__ offs, const int* __restrict__ list,
                 const float* __restrict__ slot_w, float* __restrict__ y) {
    int e = blockIdx.z;
    int base = offs[e];
    int ne = offs[e + 1] - base;
    int m0 = blockIdx.y * 128;
    if (m0 >= ne) return;
    int n0 = blockIdx.x * 128;   // d-tile

    __shared__ bf16 As[2][4096];
    __shared__ bf16 Bs[2][4096];

    int tid = threadIdx.x, lane = tid & 63, wid = tid >> 6;

    const bf16* bbase = wdT + (size_t)e * DDIM * HDIM + (size_t)n0 * HDIM;

    const bf16* aS[2]; const bf16* bS[2];
    int sdst[2];
#pragma unroll
    for (int j = 0; j < 2; ++j) {
        int q = wid + j * 4;
        int lr = q * 8 + (lane >> 3);
        int ch = (lane & 7) ^ (lr & 7);
        int rr = 2 * lr + (ch >> 2);
        int koff = (ch & 3) * 8;
        int r = m0 + rr; if (r > ne - 1) r = ne - 1;
        aS[j] = hbuf + (size_t)(base + r) * HDIM + koff;
        bS[j] = bbase + (size_t)rr * HDIM + koff;
        sdst[j] = q * 512;
    }

    int rl = lane & 15, kq = 8 * (lane >> 4);
    int wrow = (wid >> 1) * 64;
    int wcol = (wid & 1) * 64;
    int offA[4], offB[4];
#pragma unroll
    for (int mi = 0; mi < 4; ++mi) offA[mi] = frag_off(wrow + mi * 16 + rl, kq);
#pragma unroll
    for (int ni = 0; ni < 4; ++ni) offB[ni] = frag_off(wcol + ni * 16 + rl, kq);

    f32x4 zero4 = {0.f, 0.f, 0.f, 0.f};
    f32x4 acc[4][4];
#pragma unroll
    for (int mi = 0; mi < 4; ++mi)
#pragma unroll
        for (int ni = 0; ni < 4; ++ni) acc[mi][ni] = zero4;

    const int nk = HDIM / 32;   // 64

#define DN_STAGE(tt, buf)                                     \
    {                                                         \
        int k0 = (tt) * 32;                                   \
        gload16(aS[0] + k0, &As[buf][sdst[0]]);               \
        gload16(aS[1] + k0, &As[buf][sdst[1]]);               \
        gload16(bS[0] + k0, &Bs[buf][sdst[0]]);               \
        gload16(bS[1] + k0, &Bs[buf][sdst[1]]);               \
    }

    DN_STAGE(0, 0);
    DN_STAGE(1, 1);
    asm volatile("s_waitcnt vmcnt(4)" ::: "memory");
    __builtin_amdgcn_s_barrier();

    for (int t = 0; t < nk; ++t) {
        const bf16* Ab = As[t & 1];
        const bf16* Bb = Bs[t & 1];
        s16x8 a[4], b[4];
#pragma unroll
        for (int mi = 0; mi < 4; ++mi) a[mi] = *reinterpret_cast<const s16x8*>(Ab + offA[mi]);
#pragma unroll
        for (int ni = 0; ni < 4; ++ni) b[ni] = *reinterpret_cast<const s16x8*>(Bb + offB[ni]);
        __builtin_amdgcn_s_setprio(1);
#pragma unroll
        for (int mi = 0; mi < 4; ++mi)
#pragma unroll
            for (int ni = 0; ni < 4; ++ni)
                acc[mi][ni] = __builtin_amdgcn_mfma_f32_16x16x32_bf16(a[mi], b[ni], acc[mi][ni], 0, 0, 0);
        __builtin_amdgcn_s_setprio(0);
        __builtin_amdgcn_sched_barrier(0);
        __builtin_amdgcn_s_barrier();
        if (t + 2 < nk) DN_STAGE(t + 2, t & 1);
        if (t + 1 < nk) {
            if (t + 2 < nk) asm volatile("s_waitcnt vmcnt(4)" ::: "memory");
            else            asm volatile("s_waitcnt vmcnt(0)" ::: "memory");
            __builtin_amdgcn_s_barrier();
        }
    }
#undef DN_STAGE

    // epilogue: y[tok][col] += w * acc  (2 adds per element, commutative -> deterministic)
    int rbase = (lane >> 4) * 4, cbase = lane & 15;
#pragma unroll
    for (int mi = 0; mi < 4; ++mi) {
#pragma unroll
        for (int r = 0; r < 4; ++r) {
            int row = m0 + wrow + mi * 16 + rbase + r;
            if (row < ne) {
                int slot = base + row;
                int tok = list[slot];
                float w = slot_w[slot];
                float* yrow = y + (size_t)tok * DDIM + n0 + wcol + cbase;
#pragma unroll
                for (int ni = 0; ni < 4; ++ni)
                    atomicAdd(yrow + ni * 16, w * acc[mi][ni][r]);
            }
        }
    }
}

extern "C" void kernel_launch(void* const* d_in, const int* in_sizes, int n_in,
                              void* d_out, int out_size, void* d_ws, size_t ws_size,
                              hipStream_t stream) {
    const float* x  = (const float*)d_in[0];
    const float* rw = (const float*)d_in[1];
    const float* wg = (const float*)d_in[2];
    const float* wu = (const float*)d_in[3];
    const float* wd = (const float*)d_in[4];
    float* y = (float*)d_out;

    char* ws = (char*)d_ws;
    int*   r_e    = (int*)  (ws + 0);           // 2T ints
    float* r_w    = (float*)(ws + 32768);       // 2T floats
    int*   offs   = (int*)  (ws + 65600);       // 9
    int*   list   = (int*)  (ws + 65664);       // 2T ints
    float* slot_w = (float*)(ws + 98432);       // 2T floats
    bf16*  xb     = (bf16*) (ws + 1048576ull);      // 8 MB
    bf16*  wguT   = (bf16*) (ws + 16777216ull);     // 64 MB  [E][2H][D] interleaved g/u
    bf16*  wdT    = (bf16*) (ws + 83886080ull);     // 32 MB  [E][D][H]
    bf16*  hbuf   = (bf16*) (ws + 117440512ull);    // 32 MB  [slot][H]

    // weight transposes + casts (wg/wu interleaved into wguT rows 2h / 2h+1)
    transpose_cast_kernel<<<dim3(DDIM / 64, HDIM / 64, NEXP), 256, 0, stream>>>(
        wg, wguT, DDIM, HDIM, 2, 0, (size_t)2 * HDIM * DDIM);
    transpose_cast_kernel<<<dim3(DDIM / 64, HDIM / 64, NEXP), 256, 0, stream>>>(
        wu, wguT, DDIM, HDIM, 2, 1, (size_t)2 * HDIM * DDIM);
    transpose_cast_kernel<<<dim3(HDIM / 64, DDIM / 64, NEXP), 256, 0, stream>>>(
        wd, wdT, HDIM, DDIM, 1, 0, (size_t)DDIM * HDIM);

    // routing (+ fused x cast) and binning
    router_cast_kernel<<<dim3(T_TOK / 4), 256, 0, stream>>>(x, rw, r_e, r_w, xb);
    binning_kernel<<<dim3(1), 512, 0, stream>>>(r_e, r_w, offs, list, slot_w);

    // zero y (down accumulates into it atomically)
    hipMemsetAsync(d_out, 0, (size_t)out_size * sizeof(float), stream);

    // expert GEMMs (grouped, worst-case grid with early-exit)
    gateup_kernel<<<dim3(2 * HDIM / 128, T_TOK / 128, NEXP), 256, 0, stream>>>(xb, wguT, offs, list, hbuf);
    down_kernel<<<dim3(DDIM / 128, T_TOK / 128, NEXP), 256, 0, stream>>>(hbuf, wdT, offs, list, slot_w, y);
}

// Round 12
// 288.964 us; speedup vs baseline: 1.8061x; 1.0206x over previous
//
#include <hip/hip_runtime.h>
#include <hip/hip_bf16.h>

#define T_TOK 4096
#define DDIM  1024
#define HDIM  2048
#define NEXP  8
#define MAXSLOT 9216   // 2T padded: each expert base 128-aligned

typedef __attribute__((ext_vector_type(4))) float f32x4;
typedef __attribute__((ext_vector_type(8))) short s16x8;
typedef __hip_bfloat16 bf16;

typedef const void __attribute__((address_space(1))) gvoid;
typedef void __attribute__((address_space(3))) svoid;

__device__ __forceinline__ void gload16(const void* g, void* l) {
    // async global->LDS, 16B/lane; LDS dest = wave-uniform base, HW adds lane*16
    __builtin_amdgcn_global_load_lds((gvoid*)g, (svoid*)l, 16, 0, 0);
}

// Swizzled LDS layout for a [128 rows][32 k] bf16 tile in 64 ldsrows x 64 elems
// (read + staging maps correctness-proven R10/R11): row rr -> ldsrow rr>>1;
// chunk ch = 4*(rr&1) + kq/8 stored at slot ch ^ (ldsrow&7).  0 bank conflicts.
__device__ __forceinline__ int frag_off(int rr, int kq) {
    int lr = rr >> 1;
    int ch = ((rr & 1) << 2) + (kq >> 3);
    return lr * 64 + (ch ^ (lr & 7)) * 8;
}

// ---------------- router (fp64 acc, top-2 softmax) + fused x->bf16 cast ----------------
__global__ void router_cast_kernel(const float* __restrict__ x, const float* __restrict__ rw,
                                   int* __restrict__ r_e, float* __restrict__ r_w,
                                   bf16* __restrict__ xb) {
    int wave = threadIdx.x >> 6, lane = threadIdx.x & 63;
    int t = blockIdx.x * 4 + wave;
    const float* xr = x + (size_t)t * DDIM;
    bf16* xbr = xb + (size_t)t * DDIM;
    double acc[NEXP];
#pragma unroll
    for (int e = 0; e < NEXP; ++e) acc[e] = 0.0;
#pragma unroll
    for (int c = 0; c < 4; ++c) {
        int d = c * 256 + lane * 4;
        float4 v = *reinterpret_cast<const float4*>(xr + d);
        union { ushort4 u; bf16 h[4]; } o;
        o.h[0] = __float2bfloat16(v.x);
        o.h[1] = __float2bfloat16(v.y);
        o.h[2] = __float2bfloat16(v.z);
        o.h[3] = __float2bfloat16(v.w);
        *reinterpret_cast<ushort4*>(xbr + d) = o.u;
        const float* rw0 = rw + (size_t)d * NEXP;
#pragma unroll
        for (int j = 0; j < 4; ++j) {
            float xv = (&v.x)[j];
            const float* rwr = rw0 + j * NEXP;
#pragma unroll
            for (int e = 0; e < NEXP; ++e) acc[e] += (double)xv * (double)rwr[e];
        }
    }
#pragma unroll
    for (int e = 0; e < NEXP; ++e) {
#pragma unroll
        for (int off = 32; off > 0; off >>= 1) acc[e] += __shfl_down(acc[e], off);
    }
    if (lane == 0) {
        int i0 = 0; double v0 = acc[0];
#pragma unroll
        for (int e = 1; e < NEXP; ++e) if (acc[e] > v0) { v0 = acc[e]; i0 = e; }
        int i1 = -1; double v1 = -1e300;
#pragma unroll
        for (int e = 0; e < NEXP; ++e) { if (e == i0) continue; if (acc[e] > v1) { v1 = acc[e]; i1 = e; } }
        float w0 = 1.0f / (1.0f + expf((float)(v1 - v0)));
        float w1 = 1.0f - w0;
        r_e[2*t]   = i0; r_e[2*t+1] = i1;
        r_w[2*t]   = w0; r_w[2*t+1] = w1;
    }
}

// ------- fused binning: count + 128-ALIGNED scan + fill, one block -------
// offs[e] = 128-aligned base of expert e in padded slot space; cnt[e] = real count.
__global__ void binning_kernel(const int* __restrict__ r_e, const float* __restrict__ r_w,
                               int* __restrict__ offs, int* __restrict__ cnt,
                               int* __restrict__ list, float* __restrict__ slot_w) {
    __shared__ int scnt[NEXP], scur[NEXP], soff[NEXP + 1];
    int tid = threadIdx.x;
    if (tid < NEXP) { scnt[tid] = 0; scur[tid] = 0; }
    __syncthreads();
    for (int i = tid; i < 2 * T_TOK; i += 512) atomicAdd(&scnt[r_e[i]], 1);
    __syncthreads();
    if (tid == 0) {
        int s = 0;
        for (int e = 0; e < NEXP; ++e) { soff[e] = s; s += (scnt[e] + 127) & ~127; }
        soff[NEXP] = s;
    }
    __syncthreads();
    if (tid < NEXP + 1) offs[tid] = soff[tid];
    if (tid < NEXP) cnt[tid] = scnt[tid];
    for (int i = tid; i < 2 * T_TOK; i += 512) {
        int e = r_e[i];
        int pos = atomicAdd(&scur[e], 1);
        int slot = soff[e] + pos;
        list[slot] = i >> 1;
        slot_w[slot] = r_w[i];
    }
}

// ---------------- transpose + fp32->bf16 cast (vectorized both sides of global) --------
__global__ void transpose_cast_kernel(const float* __restrict__ in, bf16* __restrict__ out,
                                      int R, int C, int rmul, int roff, size_t outE) {
    __shared__ bf16 tile[64][68];
    const float* inp = in + (size_t)blockIdx.z * R * C;
    bf16* outp = out + (size_t)blockIdx.z * outE;
    int r0 = blockIdx.x * 64, c0 = blockIdx.y * 64;
    int tid = threadIdx.x;
#pragma unroll
    for (int i = 0; i < 4; ++i) {
        int idx = i * 256 + tid;
        int r = idx >> 4, c4 = (idx & 15) * 4;
        float4 v = *reinterpret_cast<const float4*>(inp + (size_t)(r0 + r) * C + c0 + c4);
        union { ushort4 u; bf16 h[4]; } o;
        o.h[0] = __float2bfloat16(v.x);
        o.h[1] = __float2bfloat16(v.y);
        o.h[2] = __float2bfloat16(v.z);
        o.h[3] = __float2bfloat16(v.w);
        *reinterpret_cast<ushort4*>(&tile[r][c4]) = o.u;   // 8B LDS write
    }
    __syncthreads();
#pragma unroll
    for (int i = 0; i < 4; ++i) {
        int idx = i * 256 + tid;
        int c = idx >> 4, r4 = (idx & 15) * 4;
        union { ushort4 u; bf16 h[4]; } w;
        w.h[0] = tile[r4 + 0][c];
        w.h[1] = tile[r4 + 1][c];
        w.h[2] = tile[r4 + 2][c];
        w.h[3] = tile[r4 + 3][c];
        *reinterpret_cast<ushort4*>(outp + ((size_t)(c0 + c) * rmul + roff) * R + r0 + r4) = w.u;
    }
}

// expert lookup in padded slot space: returns e s.t. offs[e] <= slot0 < offs[e+1]
__device__ __forceinline__ int find_expert(const int* offs, int slot0) {
    int e = 0;
#pragma unroll
    for (int i = 0; i < NEXP - 1; ++i) e += (offs[e + 1] <= slot0) ? 1 : 0;
    return e;
}

// ======== pass 1: gate+up as ONE GEMM over interleaved wguT [2H][D] ========
// 128x128 tile, BK=32, 4 waves (2M x 2N, wave-out 64x64). 32 KB dbuf LDS.
// SINGLE-barrier 2-phase (catalog T3 minimum recipe): STAGE(t+1) at top of
// iter t (buffer freed by PREVIOUS barrier; prior reads were consumed by MFMA
// before it), then ds_read+MFMA on buf[cur], then vmcnt(0)+barrier.
// Grid compacted: blockIdx.y indexes padded slot-tiles; expert found on device.
__global__ __launch_bounds__(256, 2)
void gateup_kernel(const bf16* __restrict__ xb, const bf16* __restrict__ wguT,
                   const int* __restrict__ offs, const int* __restrict__ cnt,
                   const int* __restrict__ list, bf16* __restrict__ hbuf) {
    int slot0 = blockIdx.y * 128;
    if (slot0 >= offs[NEXP]) return;
    int e = find_expert(offs, slot0);
    int base = offs[e];
    int ne = cnt[e];
    int m0 = slot0 - base;           // < ne by construction (128-aligned bases)
    int n0 = blockIdx.x * 128;       // in 2H=4096 interleaved space

    __shared__ bf16 As[2][4096];     // 128 rows x 32 k (8 KB/buf), swizzled
    __shared__ bf16 Bs[2][4096];

    int tid = threadIdx.x, lane = tid & 63, wid = tid >> 6;

    const bf16* bbase = wguT + (size_t)e * (2 * HDIM) * DDIM + (size_t)n0 * DDIM;

    // staging map (proven R10): wave-issue q writes elems q*512 + lane*8;
    // lr = q*8 + (lane>>3), slot c = lane&7 holds global chunk c^(lr&7).
    const bf16* aS[2]; const bf16* bS[2];
    int sdst[2];
#pragma unroll
    for (int j = 0; j < 2; ++j) {
        int q = wid + j * 4;
        int lr = q * 8 + (lane >> 3);
        int ch = (lane & 7) ^ (lr & 7);
        int rr = 2 * lr + (ch >> 2);
        int koff = (ch & 3) * 8;
        int r = m0 + rr; if (r > ne - 1) r = ne - 1;   // clamp: read-only, never stored
        aS[j] = xb + (size_t)list[base + r] * DDIM + koff;
        bS[j] = bbase + (size_t)rr * DDIM + koff;
        sdst[j] = q * 512;
    }

    int rl = lane & 15, kq = 8 * (lane >> 4);
    int wrow = (wid >> 1) * 64;      // 2 M waves
    int wcol = (wid & 1) * 64;       // 2 N waves
    int offA[4], offB[4];
#pragma unroll
    for (int mi = 0; mi < 4; ++mi) offA[mi] = frag_off(wrow + mi * 16 + rl, kq);
#pragma unroll
    for (int ni = 0; ni < 4; ++ni) offB[ni] = frag_off(wcol + ni * 16 + rl, kq);

    f32x4 zero4 = {0.f, 0.f, 0.f, 0.f};
    f32x4 acc[4][4];
#pragma unroll
    for (int mi = 0; mi < 4; ++mi)
#pragma unroll
        for (int ni = 0; ni < 4; ++ni) acc[mi][ni] = zero4;

    const int nk = DDIM / 32;   // 32

#define GU_STAGE(tt, buf)                                     \
    {                                                         \
        int k0 = (tt) * 32;                                   \
        gload16(aS[0] + k0, &As[buf][sdst[0]]);               \
        gload16(aS[1] + k0, &As[buf][sdst[1]]);               \
        gload16(bS[0] + k0, &Bs[buf][sdst[0]]);               \
        gload16(bS[1] + k0, &Bs[buf][sdst[1]]);               \
    }

    // prologue: stage tile 0, drain, sync
    GU_STAGE(0, 0);
    asm volatile("s_waitcnt vmcnt(0)" ::: "memory");
    __builtin_amdgcn_s_barrier();

    int cur = 0;
    for (int t = 0; t < nk; ++t) {
        if (t + 1 < nk) GU_STAGE(t + 1, cur ^ 1);     // buffer freed by previous barrier
        const bf16* Ab = As[cur];
        const bf16* Bb = Bs[cur];
        s16x8 a[4], b[4];
#pragma unroll
        for (int mi = 0; mi < 4; ++mi) a[mi] = *reinterpret_cast<const s16x8*>(Ab + offA[mi]);
#pragma unroll
        for (int ni = 0; ni < 4; ++ni) b[ni] = *reinterpret_cast<const s16x8*>(Bb + offB[ni]);
        __builtin_amdgcn_s_setprio(1);
#pragma unroll
        for (int mi = 0; mi < 4; ++mi)
#pragma unroll
            for (int ni = 0; ni < 4; ++ni)
                acc[mi][ni] = __builtin_amdgcn_mfma_f32_16x16x32_bf16(a[mi], b[ni], acc[mi][ni], 0, 0, 0);
        __builtin_amdgcn_s_setprio(0);
        __builtin_amdgcn_sched_barrier(0);
        if (t + 1 < nk) {
            asm volatile("s_waitcnt vmcnt(0)" ::: "memory");   // stage t+1 landed (issued ~600cy ago)
            __builtin_amdgcn_s_barrier();
        }
        cur ^= 1;
    }
#undef GU_STAGE

    // epilogue: even col = gate, odd col = up; pair via shfl_xor(1), even lanes store.
    int rbase = (lane >> 4) * 4, cbase = lane & 15;
    bool evenlane = (lane & 1) == 0;
#pragma unroll
    for (int mi = 0; mi < 4; ++mi) {
#pragma unroll
        for (int ni = 0; ni < 4; ++ni) {
#pragma unroll
            for (int r = 0; r < 4; ++r) {
                float own = acc[mi][ni][r];
                float oth = __shfl_xor(own, 1);
                int row = m0 + wrow + mi * 16 + rbase + r;
                if (evenlane && row < ne) {
                    float g = own, u = oth;
                    float h = (g / (1.0f + expf(-g))) * u;
                    int hcol = (n0 + wcol + ni * 16 + cbase) >> 1;
                    hbuf[(size_t)(base + row) * HDIM + hcol] = __float2bfloat16(h);
                }
            }
        }
    }
}

// ======== pass 2: down GEMM 128x128, BK=32, single-barrier 2-phase, fused atomic combine
// y zeroed first; each element gets exactly 2 commutative fp32 adds -> deterministic.
__global__ __launch_bounds__(256, 2)
void down_kernel(const bf16* __restrict__ hbuf, const bf16* __restrict__ wdT,
                 const int* __restrict__ offs, const int* __restrict__ cnt,
                 const int* __restrict__ list, const float* __restrict__ slot_w,
                 float* __restrict__ y) {
    int slot0 = blockIdx.y * 128;
    if (slot0 >= offs[NEXP]) return;
    int e = find_expert(offs, slot0);
    int base = offs[e];
    int ne = cnt[e];
    int m0 = slot0 - base;
    int n0 = blockIdx.x * 128;   // d-tile

    __shared__ bf16 As[2][4096];
    __shared__ bf16 Bs[2][4096];

    int tid = threadIdx.x, lane = tid & 63, wid = tid >> 6;

    const bf16* bbase = wdT + (size_t)e * DDIM * HDIM + (size_t)n0 * HDIM;

    const bf16* aS[2]; const bf16* bS[2];
    int sdst[2];
#pragma unroll
    for (int j = 0; j < 2; ++j) {
        int q = wid + j * 4;
        int lr = q * 8 + (lane >> 3);
        int ch = (lane & 7) ^ (lr & 7);
        int rr = 2 * lr + (ch >> 2);
        int koff = (ch & 3) * 8;
        int r = m0 + rr; if (r > ne - 1) r = ne - 1;
        aS[j] = hbuf + (size_t)(base + r) * HDIM + koff;
        bS[j] = bbase + (size_t)rr * HDIM + koff;
        sdst[j] = q * 512;
    }

    int rl = lane & 15, kq = 8 * (lane >> 4);
    int wrow = (wid >> 1) * 64;
    int wcol = (wid & 1) * 64;
    int offA[4], offB[4];
#pragma unroll
    for (int mi = 0; mi < 4; ++mi) offA[mi] = frag_off(wrow + mi * 16 + rl, kq);
#pragma unroll
    for (int ni = 0; ni < 4; ++ni) offB[ni] = frag_off(wcol + ni * 16 + rl, kq);

    f32x4 zero4 = {0.f, 0.f, 0.f, 0.f};
    f32x4 acc[4][4];
#pragma unroll
    for (int mi = 0; mi < 4; ++mi)
#pragma unroll
        for (int ni = 0; ni < 4; ++ni) acc[mi][ni] = zero4;

    const int nk = HDIM / 32;   // 64

#define DN_STAGE(tt, buf)                                     \
    {                                                         \
        int k0 = (tt) * 32;                                   \
        gload16(aS[0] + k0, &As[buf][sdst[0]]);               \
        gload16(aS[1] + k0, &As[buf][sdst[1]]);               \
        gload16(bS[0] + k0, &Bs[buf][sdst[0]]);               \
        gload16(bS[1] + k0, &Bs[buf][sdst[1]]);               \
    }

    DN_STAGE(0, 0);
    asm volatile("s_waitcnt vmcnt(0)" ::: "memory");
    __builtin_amdgcn_s_barrier();

    int cur = 0;
    for (int t = 0; t < nk; ++t) {
        if (t + 1 < nk) DN_STAGE(t + 1, cur ^ 1);
        const bf16* Ab = As[cur];
        const bf16* Bb = Bs[cur];
        s16x8 a[4], b[4];
#pragma unroll
        for (int mi = 0; mi < 4; ++mi) a[mi] = *reinterpret_cast<const s16x8*>(Ab + offA[mi]);
#pragma unroll
        for (int ni = 0; ni < 4; ++ni) b[ni] = *reinterpret_cast<const s16x8*>(Bb + offB[ni]);
        __builtin_amdgcn_s_setprio(1);
#pragma unroll
        for (int mi = 0; mi < 4; ++mi)
#pragma unroll
            for (int ni = 0; ni < 4; ++ni)
                acc[mi][ni] = __builtin_amdgcn_mfma_f32_16x16x32_bf16(a[mi], b[ni], acc[mi][ni], 0, 0, 0);
        __builtin_amdgcn_s_setprio(0);
        __builtin_amdgcn_sched_barrier(0);
        if (t + 1 < nk) {
            asm volatile("s_waitcnt vmcnt(0)" ::: "memory");
            __builtin_amdgcn_s_barrier();
        }
        cur ^= 1;
    }
#undef DN_STAGE

    // epilogue: y[tok][col] += w * acc  (2 adds per element, commutative -> deterministic)
    int rbase = (lane >> 4) * 4, cbase = lane & 15;
#pragma unroll
    for (int mi = 0; mi < 4; ++mi) {
#pragma unroll
        for (int r = 0; r < 4; ++r) {
            int row = m0 + wrow + mi * 16 + rbase + r;
            if (row < ne) {
                int slot = base + row;
                int tok = list[slot];
                float w = slot_w[slot];
                float* yrow = y + (size_t)tok * DDIM + n0 + wcol + cbase;
#pragma unroll
                for (int ni = 0; ni < 4; ++ni)
                    atomicAdd(yrow + ni * 16, w * acc[mi][ni][r]);
            }
        }
    }
}

extern "C" void kernel_launch(void* const* d_in, const int* in_sizes, int n_in,
                              void* d_out, int out_size, void* d_ws, size_t ws_size,
                              hipStream_t stream) {
    const float* x  = (const float*)d_in[0];
    const float* rw = (const float*)d_in[1];
    const float* wg = (const float*)d_in[2];
    const float* wu = (const float*)d_in[3];
    const float* wd = (const float*)d_in[4];
    float* y = (float*)d_out;

    char* ws = (char*)d_ws;
    int*   r_e    = (int*)  (ws + 0);           // 2T ints
    float* r_w    = (float*)(ws + 32768);       // 2T floats
    int*   offs   = (int*)  (ws + 65600);       // 9 (padded bases)
    int*   cnt    = (int*)  (ws + 65544 + 96);  // 8 real counts (at 65640)
    int*   list   = (int*)  (ws + 65664 + 128); // MAXSLOT ints
    float* slot_w = (float*)(ws + 65664 + 128 + 4 * MAXSLOT);  // MAXSLOT floats
    bf16*  xb     = (bf16*) (ws + 1048576ull);      // 8 MB
    bf16*  wguT   = (bf16*) (ws + 16777216ull);     // 64 MB  [E][2H][D] interleaved g/u
    bf16*  wdT    = (bf16*) (ws + 83886080ull);     // 32 MB  [E][D][H]
    bf16*  hbuf   = (bf16*) (ws + 117440512ull);    // 37.75 MB [MAXSLOT][H] (end ~155 MB)

    // weight transposes + casts (wg/wu interleaved into wguT rows 2h / 2h+1)
    transpose_cast_kernel<<<dim3(DDIM / 64, HDIM / 64, NEXP), 256, 0, stream>>>(
        wg, wguT, DDIM, HDIM, 2, 0, (size_t)2 * HDIM * DDIM);
    transpose_cast_kernel<<<dim3(DDIM / 64, HDIM / 64, NEXP), 256, 0, stream>>>(
        wu, wguT, DDIM, HDIM, 2, 1, (size_t)2 * HDIM * DDIM);
    transpose_cast_kernel<<<dim3(HDIM / 64, DDIM / 64, NEXP), 256, 0, stream>>>(
        wd, wdT, HDIM, DDIM, 1, 0, (size_t)DDIM * HDIM);

    // routing (+ fused x cast) and padded binning
    router_cast_kernel<<<dim3(T_TOK / 4), 256, 0, stream>>>(x, rw, r_e, r_w, xb);
    binning_kernel<<<dim3(1), 512, 0, stream>>>(r_e, r_w, offs, cnt, list, slot_w);

    // zero y (down accumulates into it atomically)
    hipMemsetAsync(d_out, 0, (size_t)out_size * sizeof(float), stream);

    // expert GEMMs, compacted grids over padded slot-tiles (72 worst-case)
    gateup_kernel<<<dim3(2 * HDIM / 128, MAXSLOT / 128, 1), 256, 0, stream>>>(
        xb, wguT, offs, cnt, list, hbuf);
    down_kernel<<<dim3(DDIM / 128, MAXSLOT / 128, 1), 256, 0, stream>>>(
        hbuf, wdT, offs, cnt, list, slot_w, y);
}

// Round 13
// 286.211 us; speedup vs baseline: 1.8235x; 1.0096x over previous
//
#include <hip/hip_runtime.h>
#include <hip/hip_bf16.h>

#define T_TOK 4096
#define DDIM  1024
#define HDIM  2048
#define NEXP  8
#define MAXSLOT 9216   // 2T padded: each expert base 128-aligned

typedef __attribute__((ext_vector_type(4))) float f32x4;
typedef __attribute__((ext_vector_type(8))) short s16x8;
typedef __hip_bfloat16 bf16;

typedef const void __attribute__((address_space(1))) gvoid;
typedef void __attribute__((address_space(3))) svoid;

__device__ __forceinline__ void gload16(const void* g, void* l) {
    // async global->LDS, 16B/lane; LDS dest = wave-uniform base, HW adds lane*16
    __builtin_amdgcn_global_load_lds((gvoid*)g, (svoid*)l, 16, 0, 0);
}

// Swizzled LDS layout for a [128 rows][32 k] bf16 tile in 64 ldsrows x 64 elems
// (read + staging maps correctness-proven R10-R12): row rr -> ldsrow rr>>1;
// chunk ch = 4*(rr&1) + kq/8 stored at slot ch ^ (ldsrow&7).  0 bank conflicts.
__device__ __forceinline__ int frag_off(int rr, int kq) {
    int lr = rr >> 1;
    int ch = ((rr & 1) << 2) + (kq >> 3);
    return lr * 64 + (ch ^ (lr & 7)) * 8;
}

// ---------------- router (fp64 acc, top-2 softmax) + fused x->bf16 cast ----------------
__global__ void router_cast_kernel(const float* __restrict__ x, const float* __restrict__ rw,
                                   int* __restrict__ r_e, float* __restrict__ r_w,
                                   bf16* __restrict__ xb) {
    int wave = threadIdx.x >> 6, lane = threadIdx.x & 63;
    int t = blockIdx.x * 4 + wave;
    const float* xr = x + (size_t)t * DDIM;
    bf16* xbr = xb + (size_t)t * DDIM;
    double acc[NEXP];
#pragma unroll
    for (int e = 0; e < NEXP; ++e) acc[e] = 0.0;
#pragma unroll
    for (int c = 0; c < 4; ++c) {
        int d = c * 256 + lane * 4;
        float4 v = *reinterpret_cast<const float4*>(xr + d);
        union { ushort4 u; bf16 h[4]; } o;
        o.h[0] = __float2bfloat16(v.x);
        o.h[1] = __float2bfloat16(v.y);
        o.h[2] = __float2bfloat16(v.z);
        o.h[3] = __float2bfloat16(v.w);
        *reinterpret_cast<ushort4*>(xbr + d) = o.u;
        const float* rw0 = rw + (size_t)d * NEXP;
#pragma unroll
        for (int j = 0; j < 4; ++j) {
            float xv = (&v.x)[j];
            const float* rwr = rw0 + j * NEXP;
#pragma unroll
            for (int e = 0; e < NEXP; ++e) acc[e] += (double)xv * (double)rwr[e];
        }
    }
#pragma unroll
    for (int e = 0; e < NEXP; ++e) {
#pragma unroll
        for (int off = 32; off > 0; off >>= 1) acc[e] += __shfl_down(acc[e], off);
    }
    if (lane == 0) {
        int i0 = 0; double v0 = acc[0];
#pragma unroll
        for (int e = 1; e < NEXP; ++e) if (acc[e] > v0) { v0 = acc[e]; i0 = e; }
        int i1 = -1; double v1 = -1e300;
#pragma unroll
        for (int e = 0; e < NEXP; ++e) { if (e == i0) continue; if (acc[e] > v1) { v1 = acc[e]; i1 = e; } }
        float w0 = 1.0f / (1.0f + expf((float)(v1 - v0)));
        float w1 = 1.0f - w0;
        r_e[2*t]   = i0; r_e[2*t+1] = i1;
        r_w[2*t]   = w0; r_w[2*t+1] = w1;
    }
}

// ------- fused binning: count + 128-ALIGNED scan + fill, one block -------
__global__ void binning_kernel(const int* __restrict__ r_e, const float* __restrict__ r_w,
                               int* __restrict__ offs, int* __restrict__ cnt,
                               int* __restrict__ list, float* __restrict__ slot_w) {
    __shared__ int scnt[NEXP], scur[NEXP], soff[NEXP + 1];
    int tid = threadIdx.x;
    if (tid < NEXP) { scnt[tid] = 0; scur[tid] = 0; }
    __syncthreads();
    for (int i = tid; i < 2 * T_TOK; i += 512) atomicAdd(&scnt[r_e[i]], 1);
    __syncthreads();
    if (tid == 0) {
        int s = 0;
        for (int e = 0; e < NEXP; ++e) { soff[e] = s; s += (scnt[e] + 127) & ~127; }
        soff[NEXP] = s;
    }
    __syncthreads();
    if (tid < NEXP + 1) offs[tid] = soff[tid];
    if (tid < NEXP) cnt[tid] = scnt[tid];
    for (int i = tid; i < 2 * T_TOK; i += 512) {
        int e = r_e[i];
        int pos = atomicAdd(&scur[e], 1);
        int slot = soff[e] + pos;
        list[slot] = i >> 1;
        slot_w[slot] = r_w[i];
    }
}

// -------- wg+wu transpose+cast in ONE launch: z in [0,16), which = z>>3 -> roff --------
__global__ void transpose_gu_kernel(const float* __restrict__ wg, const float* __restrict__ wu,
                                    bf16* __restrict__ wguT) {
    __shared__ bf16 tile[64][68];
    int which = blockIdx.z >> 3;            // 0 = gate, 1 = up
    int e = blockIdx.z & 7;
    const float* inp = (which ? wu : wg) + (size_t)e * DDIM * HDIM;
    bf16* outp = wguT + (size_t)e * 2 * HDIM * DDIM;
    int r0 = blockIdx.x * 64, c0 = blockIdx.y * 64;   // r over D, c over H
    int tid = threadIdx.x;
#pragma unroll
    for (int i = 0; i < 4; ++i) {
        int idx = i * 256 + tid;
        int r = idx >> 4, c4 = (idx & 15) * 4;
        float4 v = *reinterpret_cast<const float4*>(inp + (size_t)(r0 + r) * HDIM + c0 + c4);
        union { ushort4 u; bf16 h[4]; } o;
        o.h[0] = __float2bfloat16(v.x);
        o.h[1] = __float2bfloat16(v.y);
        o.h[2] = __float2bfloat16(v.z);
        o.h[3] = __float2bfloat16(v.w);
        *reinterpret_cast<ushort4*>(&tile[r][c4]) = o.u;
    }
    __syncthreads();
#pragma unroll
    for (int i = 0; i < 4; ++i) {
        int idx = i * 256 + tid;
        int c = idx >> 4, r4 = (idx & 15) * 4;
        union { ushort4 u; bf16 h[4]; } w;
        w.h[0] = tile[r4 + 0][c];
        w.h[1] = tile[r4 + 1][c];
        w.h[2] = tile[r4 + 2][c];
        w.h[3] = tile[r4 + 3][c];
        // interleaved row 2h+which
        *reinterpret_cast<ushort4*>(outp + ((size_t)(c0 + c) * 2 + which) * DDIM + r0 + r4) = w.u;
    }
}

// -------- wd transpose+cast: [E][H][D] -> [E][D][H] --------
__global__ void transpose_wd_kernel(const float* __restrict__ wd, bf16* __restrict__ wdT) {
    __shared__ bf16 tile[64][68];
    const float* inp = wd + (size_t)blockIdx.z * HDIM * DDIM;
    bf16* outp = wdT + (size_t)blockIdx.z * DDIM * HDIM;
    int r0 = blockIdx.x * 64, c0 = blockIdx.y * 64;   // r over H, c over D
    int tid = threadIdx.x;
#pragma unroll
    for (int i = 0; i < 4; ++i) {
        int idx = i * 256 + tid;
        int r = idx >> 4, c4 = (idx & 15) * 4;
        float4 v = *reinterpret_cast<const float4*>(inp + (size_t)(r0 + r) * DDIM + c0 + c4);
        union { ushort4 u; bf16 h[4]; } o;
        o.h[0] = __float2bfloat16(v.x);
        o.h[1] = __float2bfloat16(v.y);
        o.h[2] = __float2bfloat16(v.z);
        o.h[3] = __float2bfloat16(v.w);
        *reinterpret_cast<ushort4*>(&tile[r][c4]) = o.u;
    }
    __syncthreads();
#pragma unroll
    for (int i = 0; i < 4; ++i) {
        int idx = i * 256 + tid;
        int c = idx >> 4, r4 = (idx & 15) * 4;
        union { ushort4 u; bf16 h[4]; } w;
        w.h[0] = tile[r4 + 0][c];
        w.h[1] = tile[r4 + 1][c];
        w.h[2] = tile[r4 + 2][c];
        w.h[3] = tile[r4 + 3][c];
        *reinterpret_cast<ushort4*>(outp + (size_t)(c0 + c) * HDIM + r0 + r4) = w.u;
    }
}

// expert lookup in padded slot space
__device__ __forceinline__ int find_expert(const int* offs, int slot0) {
    int e = 0;
#pragma unroll
    for (int i = 0; i < NEXP - 1; ++i) e += (offs[e + 1] <= slot0) ? 1 : 0;
    return e;
}

// ======== pass 1: gate+up as ONE GEMM over interleaved wguT [2H][D] ========
// 128x128 tile, BK=32, 4 waves (2M x 2N, wave-out 64x64). DEPTH-3 pipeline:
// 3 LDS buffers (48 KB -> 3 blocks/CU). Iter t: stage t+2 -> buf (t+2)%3
// (freed by end-of-(t-1) barrier), compute buf t%3, then vmcnt(4) (t+1 landed,
// t+2 in flight) + ONE barrier. Tile t+1 gets ~2 iterations of latency budget.
__global__ __launch_bounds__(256, 2)
void gateup_kernel(const bf16* __restrict__ xb, const bf16* __restrict__ wguT,
                   const int* __restrict__ offs, const int* __restrict__ cnt,
                   const int* __restrict__ list, bf16* __restrict__ hbuf) {
    int slot0 = blockIdx.y * 128;
    if (slot0 >= offs[NEXP]) return;
    int e = find_expert(offs, slot0);
    int base = offs[e];
    int ne = cnt[e];
    int m0 = slot0 - base;
    int n0 = blockIdx.x * 128;       // in 2H=4096 interleaved space

    __shared__ bf16 As[3][4096];     // 3 bufs x 8 KB, swizzled
    __shared__ bf16 Bs[3][4096];

    int tid = threadIdx.x, lane = tid & 63, wid = tid >> 6;

    const bf16* bbase = wguT + (size_t)e * (2 * HDIM) * DDIM + (size_t)n0 * DDIM;

    // staging map (proven R10): wave-issue q writes elems q*512 + lane*8;
    // lr = q*8 + (lane>>3), slot c = lane&7 holds global chunk c^(lr&7).
    const bf16* aS[2]; const bf16* bS[2];
    int sdst[2];
#pragma unroll
    for (int j = 0; j < 2; ++j) {
        int q = wid + j * 4;
        int lr = q * 8 + (lane >> 3);
        int ch = (lane & 7) ^ (lr & 7);
        int rr = 2 * lr + (ch >> 2);
        int koff = (ch & 3) * 8;
        int r = m0 + rr; if (r > ne - 1) r = ne - 1;   // clamp: read-only, never stored
        aS[j] = xb + (size_t)list[base + r] * DDIM + koff;
        bS[j] = bbase + (size_t)rr * DDIM + koff;
        sdst[j] = q * 512;
    }

    int rl = lane & 15, kq = 8 * (lane >> 4);
    int wrow = (wid >> 1) * 64;      // 2 M waves
    int wcol = (wid & 1) * 64;       // 2 N waves
    int offA[4], offB[4];
#pragma unroll
    for (int mi = 0; mi < 4; ++mi) offA[mi] = frag_off(wrow + mi * 16 + rl, kq);
#pragma unroll
    for (int ni = 0; ni < 4; ++ni) offB[ni] = frag_off(wcol + ni * 16 + rl, kq);

    f32x4 zero4 = {0.f, 0.f, 0.f, 0.f};
    f32x4 acc[4][4];
#pragma unroll
    for (int mi = 0; mi < 4; ++mi)
#pragma unroll
        for (int ni = 0; ni < 4; ++ni) acc[mi][ni] = zero4;

    const int nk = DDIM / 32;   // 32

#define GU_STAGE(tt, buf)                                     \
    {                                                         \
        int k0 = (tt) * 32;                                   \
        gload16(aS[0] + k0, &As[buf][sdst[0]]);               \
        gload16(aS[1] + k0, &As[buf][sdst[1]]);               \
        gload16(bS[0] + k0, &Bs[buf][sdst[0]]);               \
        gload16(bS[1] + k0, &Bs[buf][sdst[1]]);               \
    }

    // prologue: stage tiles 0,1; wait tile0 (tile1's 4 loads stay in flight)
    GU_STAGE(0, 0);
    GU_STAGE(1, 1);
    asm volatile("s_waitcnt vmcnt(4)" ::: "memory");
    __builtin_amdgcn_s_barrier();

    int cb = 0;                      // compute-buffer index (t % 3)
    for (int t = 0; t < nk; ++t) {
        int sb = cb + 2; if (sb >= 3) sb -= 3;         // (t+2) % 3
        if (t + 2 < nk) GU_STAGE(t + 2, sb);           // freed by end-of-(t-1) barrier
        const bf16* Ab = As[cb];
        const bf16* Bb = Bs[cb];
        s16x8 a[4], b[4];
#pragma unroll
        for (int mi = 0; mi < 4; ++mi) a[mi] = *reinterpret_cast<const s16x8*>(Ab + offA[mi]);
#pragma unroll
        for (int ni = 0; ni < 4; ++ni) b[ni] = *reinterpret_cast<const s16x8*>(Bb + offB[ni]);
        __builtin_amdgcn_s_setprio(1);
#pragma unroll
        for (int mi = 0; mi < 4; ++mi)
#pragma unroll
            for (int ni = 0; ni < 4; ++ni)
                acc[mi][ni] = __builtin_amdgcn_mfma_f32_16x16x32_bf16(a[mi], b[ni], acc[mi][ni], 0, 0, 0);
        __builtin_amdgcn_s_setprio(0);
        __builtin_amdgcn_sched_barrier(0);
        if (t + 1 < nk) {
            // t+1 staged 2 iters ago -> landed; t+2 (4 loads) stays in flight
            if (t + 2 < nk) asm volatile("s_waitcnt vmcnt(4)" ::: "memory");
            else            asm volatile("s_waitcnt vmcnt(0)" ::: "memory");
            __builtin_amdgcn_s_barrier();
        }
        cb = cb + 1; if (cb >= 3) cb -= 3;
    }
#undef GU_STAGE

    // epilogue: even col = gate, odd col = up; pair via shfl_xor(1), even lanes store.
    int rbase = (lane >> 4) * 4, cbase = lane & 15;
    bool evenlane = (lane & 1) == 0;
#pragma unroll
    for (int mi = 0; mi < 4; ++mi) {
#pragma unroll
        for (int ni = 0; ni < 4; ++ni) {
#pragma unroll
            for (int r = 0; r < 4; ++r) {
                float own = acc[mi][ni][r];
                float oth = __shfl_xor(own, 1);
                int row = m0 + wrow + mi * 16 + rbase + r;
                if (evenlane && row < ne) {
                    float g = own, u = oth;
                    float h = (g / (1.0f + expf(-g))) * u;
                    int hcol = (n0 + wcol + ni * 16 + cbase) >> 1;
                    hbuf[(size_t)(base + row) * HDIM + hcol] = __float2bfloat16(h);
                }
            }
        }
    }
}

// ======== pass 2: down GEMM 128x128, BK=32, depth-3 pipeline, fused atomic combine ====
// y zeroed first; each element gets exactly 2 commutative fp32 adds -> deterministic.
__global__ __launch_bounds__(256, 2)
void down_kernel(const bf16* __restrict__ hbuf, const bf16* __restrict__ wdT,
                 const int* __restrict__ offs, const int* __restrict__ cnt,
                 const int* __restrict__ list, const float* __restrict__ slot_w,
                 float* __restrict__ y) {
    int slot0 = blockIdx.y * 128;
    if (slot0 >= offs[NEXP]) return;
    int e = find_expert(offs, slot0);
    int base = offs[e];
    int ne = cnt[e];
    int m0 = slot0 - base;
    int n0 = blockIdx.x * 128;   // d-tile

    __shared__ bf16 As[3][4096];
    __shared__ bf16 Bs[3][4096];

    int tid = threadIdx.x, lane = tid & 63, wid = tid >> 6;

    const bf16* bbase = wdT + (size_t)e * DDIM * HDIM + (size_t)n0 * HDIM;

    const bf16* aS[2]; const bf16* bS[2];
    int sdst[2];
#pragma unroll
    for (int j = 0; j < 2; ++j) {
        int q = wid + j * 4;
        int lr = q * 8 + (lane >> 3);
        int ch = (lane & 7) ^ (lr & 7);
        int rr = 2 * lr + (ch >> 2);
        int koff = (ch & 3) * 8;
        int r = m0 + rr; if (r > ne - 1) r = ne - 1;
        aS[j] = hbuf + (size_t)(base + r) * HDIM + koff;
        bS[j] = bbase + (size_t)rr * HDIM + koff;
        sdst[j] = q * 512;
    }

    int rl = lane & 15, kq = 8 * (lane >> 4);
    int wrow = (wid >> 1) * 64;
    int wcol = (wid & 1) * 64;
    int offA[4], offB[4];
#pragma unroll
    for (int mi = 0; mi < 4; ++mi) offA[mi] = frag_off(wrow + mi * 16 + rl, kq);
#pragma unroll
    for (int ni = 0; ni < 4; ++ni) offB[ni] = frag_off(wcol + ni * 16 + rl, kq);

    f32x4 zero4 = {0.f, 0.f, 0.f, 0.f};
    f32x4 acc[4][4];
#pragma unroll
    for (int mi = 0; mi < 4; ++mi)
#pragma unroll
        for (int ni = 0; ni < 4; ++ni) acc[mi][ni] = zero4;

    const int nk = HDIM / 32;   // 64

#define DN_STAGE(tt, buf)                                     \
    {                                                         \
        int k0 = (tt) * 32;                                   \
        gload16(aS[0] + k0, &As[buf][sdst[0]]);               \
        gload16(aS[1] + k0, &As[buf][sdst[1]]);               \
        gload16(bS[0] + k0, &Bs[buf][sdst[0]]);               \
        gload16(bS[1] + k0, &Bs[buf][sdst[1]]);               \
    }

    DN_STAGE(0, 0);
    DN_STAGE(1, 1);
    asm volatile("s_waitcnt vmcnt(4)" ::: "memory");
    __builtin_amdgcn_s_barrier();

    int cb = 0;
    for (int t = 0; t < nk; ++t) {
        int sb = cb + 2; if (sb >= 3) sb -= 3;
        if (t + 2 < nk) DN_STAGE(t + 2, sb);
        const bf16* Ab = As[cb];
        const bf16* Bb = Bs[cb];
        s16x8 a[4], b[4];
#pragma unroll
        for (int mi = 0; mi < 4; ++mi) a[mi] = *reinterpret_cast<const s16x8*>(Ab + offA[mi]);
#pragma unroll
        for (int ni = 0; ni < 4; ++ni) b[ni] = *reinterpret_cast<const s16x8*>(Bb + offB[ni]);
        __builtin_amdgcn_s_setprio(1);
#pragma unroll
        for (int mi = 0; mi < 4; ++mi)
#pragma unroll
            for (int ni = 0; ni < 4; ++ni)
                acc[mi][ni] = __builtin_amdgcn_mfma_f32_16x16x32_bf16(a[mi], b[ni], acc[mi][ni], 0, 0, 0);
        __builtin_amdgcn_s_setprio(0);
        __builtin_amdgcn_sched_barrier(0);
        if (t + 1 < nk) {
            if (t + 2 < nk) asm volatile("s_waitcnt vmcnt(4)" ::: "memory");
            else            asm volatile("s_waitcnt vmcnt(0)" ::: "memory");
            __builtin_amdgcn_s_barrier();
        }
        cb = cb + 1; if (cb >= 3) cb -= 3;
    }
#undef DN_STAGE

    // epilogue: y[tok][col] += w * acc  (2 adds per element, commutative -> deterministic)
    int rbase = (lane >> 4) * 4, cbase = lane & 15;
#pragma unroll
    for (int mi = 0; mi < 4; ++mi) {
#pragma unroll
        for (int r = 0; r < 4; ++r) {
            int row = m0 + wrow + mi * 16 + rbase + r;
            if (row < ne) {
                int slot = base + row;
                int tok = list[slot];
                float w = slot_w[slot];
                float* yrow = y + (size_t)tok * DDIM + n0 + wcol + cbase;
#pragma unroll
                for (int ni = 0; ni < 4; ++ni)
                    atomicAdd(yrow + ni * 16, w * acc[mi][ni][r]);
            }
        }
    }
}

extern "C" void kernel_launch(void* const* d_in, const int* in_sizes, int n_in,
                              void* d_out, int out_size, void* d_ws, size_t ws_size,
                              hipStream_t stream) {
    const float* x  = (const float*)d_in[0];
    const float* rw = (const float*)d_in[1];
    const float* wg = (const float*)d_in[2];
    const float* wu = (const float*)d_in[3];
    const float* wd = (const float*)d_in[4];
    float* y = (float*)d_out;

    char* ws = (char*)d_ws;
    int*   r_e    = (int*)  (ws + 0);           // 2T ints
    float* r_w    = (float*)(ws + 32768);       // 2T floats
    int*   offs   = (int*)  (ws + 65600);       // 9 (padded bases)
    int*   cnt    = (int*)  (ws + 65640);       // 8 real counts
    int*   list   = (int*)  (ws + 65792);       // MAXSLOT ints
    float* slot_w = (float*)(ws + 65792 + 4 * MAXSLOT);  // MAXSLOT floats
    bf16*  xb     = (bf16*) (ws + 1048576ull);      // 8 MB
    bf16*  wguT   = (bf16*) (ws + 16777216ull);     // 64 MB  [E][2H][D] interleaved g/u
    bf16*  wdT    = (bf16*) (ws + 83886080ull);     // 32 MB  [E][D][H]
    bf16*  hbuf   = (bf16*) (ws + 117440512ull);    // 37.75 MB [MAXSLOT][H]

    // weight transposes + casts (wg+wu in one launch; wd separate)
    transpose_gu_kernel<<<dim3(DDIM / 64, HDIM / 64, 2 * NEXP), 256, 0, stream>>>(wg, wu, wguT);
    transpose_wd_kernel<<<dim3(HDIM / 64, DDIM / 64, NEXP), 256, 0, stream>>>(wd, wdT);

    // routing (+ fused x cast) and padded binning
    router_cast_kernel<<<dim3(T_TOK / 4), 256, 0, stream>>>(x, rw, r_e, r_w, xb);
    binning_kernel<<<dim3(1), 512, 0, stream>>>(r_e, r_w, offs, cnt, list, slot_w);

    // zero y (down accumulates into it atomically)
    hipMemsetAsync(d_out, 0, (size_t)out_size * sizeof(float), stream);

    // expert GEMMs, compacted grids over padded slot-tiles (72 worst-case)
    gateup_kernel<<<dim3(2 * HDIM / 128, MAXSLOT / 128, 1), 256, 0, stream>>>(
        xb, wguT, offs, cnt, list, hbuf);
    down_kernel<<<dim3(DDIM / 128, MAXSLOT / 128, 1), 256, 0, stream>>>(
        hbuf, wdT, offs, cnt, list, slot_w, y);
}